// Round 8
// baseline (183.938 us; speedup 1.0000x reference)
//
#include <hip/hip_runtime.h>

#define Bsz 8
#define Ssz 4096
#define Dsz 128

typedef short bf16x8 __attribute__((ext_vector_type(8)));
typedef float f32x4 __attribute__((ext_vector_type(4)));
typedef float f32x16 __attribute__((ext_vector_type(16)));
typedef int i32x2 __attribute__((ext_vector_type(2)));
typedef int i32x4 __attribute__((ext_vector_type(4)));
typedef unsigned int u32;

union B8 { u32 u[4]; bf16x8 v; };

// pack two fp32 -> bf16x2 (round half-up)
__device__ __forceinline__ u32 pkbf(float a, float b) {
  u32 ra = __float_as_uint(a) + 0x8000u;
  u32 rb = __float_as_uint(b) + 0x8000u;
  return __builtin_amdgcn_perm(rb, ra, 0x07060302u);
}
__device__ __forceinline__ short f2bf(float f) {
  u32 r = __float_as_uint(f) + 0x8000u;
  return (short)(r >> 16);
}

__device__ __forceinline__ void gll16(const void* g, void* l) {
  __builtin_amdgcn_global_load_lds((const __attribute__((address_space(1))) void*)g,
                                   (__attribute__((address_space(3))) void*)l, 16, 0, 0);
}

// Staged Q/K layout (bf16), per 64-row tile (16KB): [gd 0..15][s 0..63][8 d].
// V is plain row-major [s][d].

// stage one 64-row K tile (16KB) via async DMA; 4 waves x 4 x 1KB
#define STAGE_K(it_, bf_)                                                     \
  { const char* src_ = kbase + (size_t)(it_) * 16384;                         \
    _Pragma("unroll")                                                         \
    for (int i_ = 0; i_ < 4; ++i_) {                                          \
      int p_ = wv * 4 + i_;                                                   \
      gll16(src_ + p_ * 1024 + lane * 16, (char*)kbuf[bf_] + p_ * 1024);      \
    } }

// ---------------- Projection ----------------
// grid 512 (64-row X tiles), 4 waves (wave owns e-slice 32). Operands in registers;
// LDS only for output assembly.
__global__ __launch_bounds__(256, 2) void proj_kernel(
    const float* __restrict__ x, const float* __restrict__ wsrc,
    short* __restrict__ Qs, short* __restrict__ Ks, short* __restrict__ Vp) {
  __shared__ short ob[8192];  // 16KB output assembly

  const int rb = blockIdx.x;
  const int t = threadIdx.x;
  const int wv = t >> 6, lane = t & 63, l31 = lane & 31, h = lane >> 5;

  // X frags: [st 2][c 8]: lane = s row (l31), k = d = c*16 + 8h + j
  bf16x8 xf[2][8];
  {
    const float* xs = x + (size_t)rb * 64 * Dsz;
    #pragma unroll
    for (int st = 0; st < 2; ++st)
      #pragma unroll
      for (int c = 0; c < 8; ++c) {
        const float* p = xs + (st * 32 + l31) * Dsz + c * 16 + 8 * h;
        f32x4 v0 = *(const f32x4*)p;
        f32x4 v1 = *(const f32x4*)(p + 4);
        B8 tmp;
        tmp.u[0] = pkbf(v0[0], v0[1]); tmp.u[1] = pkbf(v0[2], v0[3]);
        tmp.u[2] = pkbf(v1[0], v1[1]); tmp.u[3] = pkbf(v1[2], v1[3]);
        xf[st][c] = tmp.v;
      }
  }

  for (int mat = 0; mat < 3; ++mat) {
    const float* wm = wsrc + (size_t)mat * Dsz * Dsz;
    const float scale = (mat == 0) ? 1.44269504088896340736f : 1.0f;  // log2e in Wq
    bf16x8 wf[8];  // lane = e (wv*32+l31), k = d = c*16+8h+j (coalesced)
    #pragma unroll
    for (int c = 0; c < 8; ++c) {
      const float* p = wm + (size_t)(c * 16 + 8 * h) * Dsz + wv * 32 + l31;
      B8 tmp;
      #pragma unroll
      for (int j = 0; j < 4; ++j)
        tmp.u[j] = pkbf(p[(2 * j) * Dsz] * scale, p[(2 * j + 1) * Dsz] * scale);
      wf[c] = tmp.v;
    }

    if (mat < 2) {
      // C^T[e][s] = W(A,m=e) x X(B,n=s): col=lane&31=s, row=e -> staged [ge][s][8e]
      #pragma unroll
      for (int st = 0; st < 2; ++st) {
        f32x16 acc = {};
        #pragma unroll
        for (int c = 0; c < 8; ++c)
          acc = __builtin_amdgcn_mfma_f32_32x32x16_bf16(wf[c], xf[st][c], acc, 0, 0, 0);
        #pragma unroll
        for (int g = 0; g < 4; ++g) {
          int e0 = wv * 32 + 8 * g + 4 * h;
          int s = st * 32 + l31;
          i32x2 pr;
          pr[0] = pkbf(acc[4 * g + 0], acc[4 * g + 1]);
          pr[1] = pkbf(acc[4 * g + 2], acc[4 * g + 3]);
          *(i32x2*)&ob[(e0 >> 3) * 512 + s * 8 + (e0 & 7)] = pr;
        }
      }
    } else {
      // C[s][e] = X(A,m=s) x W(B,n=e): col=lane&31=e, row=s -> row-major ob[s][e]
      #pragma unroll
      for (int st = 0; st < 2; ++st) {
        f32x16 acc = {};
        #pragma unroll
        for (int c = 0; c < 8; ++c)
          acc = __builtin_amdgcn_mfma_f32_32x32x16_bf16(xf[st][c], wf[c], acc, 0, 0, 0);
        int e = wv * 32 + l31;
        #pragma unroll
        for (int r = 0; r < 16; ++r) {
          int s = st * 32 + (r & 3) + 8 * (r >> 2) + 4 * h;
          ob[s * 128 + e] = f2bf(acc[r]);
        }
      }
    }
    __syncthreads();
    short* dst = (mat == 0 ? Qs : mat == 1 ? Ks : Vp) + (size_t)rb * 8192;
    #pragma unroll
    for (int p = 0; p < 4; ++p)
      *(i32x4*)&dst[(p * 256 + t) * 8] = *(const i32x4*)&ob[(p * 256 + t) * 8];
    __syncthreads();
  }
}

// ---------------- Phase A: softmax denominators ----------------
// grid (8 b, 16 qt, 8 kt): q-tile 256 (wave owns 64 q), k-range 512, chunks of 64.
__global__ __launch_bounds__(256, 4) void lsum_kernel(
    const short* __restrict__ Qs, const short* __restrict__ Ks,
    float* __restrict__ lpart) {
  __shared__ short kbuf[2][8192];

  const int b = blockIdx.x, qt = blockIdx.y, kt = blockIdx.z;
  const int t = threadIdx.x;
  const int wv = t >> 6, lane = t & 63, l31 = lane & 31, h = lane >> 5;

  // Q B-frags: lane = q, k = d
  bf16x8 qf[2][8];
  {
    const short* qsrc = Qs + (size_t)(b * 64 + qt * 4 + wv) * 8192;
    #pragma unroll
    for (int nq = 0; nq < 2; ++nq)
      #pragma unroll
      for (int c = 0; c < 8; ++c)
        qf[nq][c] = *(const bf16x8*)&qsrc[(2 * c + h) * 512 + (nq * 32 + l31) * 8];
  }
  float rs2[2] = {0.f, 0.f};

  const char* kbase = (const char*)(Ks + (size_t)(b * 64 + kt * 8) * 8192);
  STAGE_K(0, 0);
  __syncthreads();

  for (int it = 0; it < 8; ++it) {
    const int cur = it & 1;
    if (it < 7) STAGE_K(it + 1, cur ^ 1);
    #pragma unroll
    for (int mk = 0; mk < 2; ++mk) {
      bf16x8 kf[8];  // A-frags: lane = k-row
      #pragma unroll
      for (int c = 0; c < 8; ++c)
        kf[c] = *(const bf16x8*)&kbuf[cur][(2 * c + h) * 512 + (mk * 32 + l31) * 8];
      f32x16 s0 = {}, s1 = {};
      #pragma unroll
      for (int c = 0; c < 8; ++c) {
        s0 = __builtin_amdgcn_mfma_f32_32x32x16_bf16(kf[c], qf[0][c], s0, 0, 0, 0);
        s1 = __builtin_amdgcn_mfma_f32_32x32x16_bf16(kf[c], qf[1][c], s1, 0, 0, 0);
      }
      #pragma unroll
      for (int r = 0; r < 16; ++r) rs2[0] += __builtin_amdgcn_exp2f(s0[r]);
      #pragma unroll
      for (int r = 0; r < 16; ++r) rs2[1] += __builtin_amdgcn_exp2f(s1[r]);
    }
    __syncthreads();
  }

  #pragma unroll
  for (int nq = 0; nq < 2; ++nq) {
    float v = rs2[nq] + __shfl_xor(rs2[nq], 32, 64);
    if (h == 0)
      lpart[((size_t)kt * 8 + b) * 4096 + qt * 256 + wv * 64 + nq * 32 + l31] = v;
  }
}

// ---------------- Phase B: g-partials: gpart[b,qt,kt][k] = sum_{q in tile} linv[q] exp(S) ----
__global__ __launch_bounds__(256, 3) void attnv_kernel(
    const short* __restrict__ Qs, const short* __restrict__ Ks,
    const float* __restrict__ lpart, float* __restrict__ gpart) {
  __shared__ short kbuf[2][8192];
  __shared__ float linv_lds[256];
  __shared__ float gw[4][512];

  const int b = blockIdx.x, qt = blockIdx.y, kt = blockIdx.z;
  const int t = threadIdx.x;
  const int wv = t >> 6, lane = t & 63, l31 = lane & 31, h = lane >> 5;

  {  // denominators for this block's 256 q (sum over 8 kt partials)
    int q = qt * 256 + t;
    float l = 0.f;
    #pragma unroll
    for (int k2 = 0; k2 < 8; ++k2) l += lpart[((size_t)k2 * 8 + b) * 4096 + q];
    linv_lds[t] = 1.f / (l * (float)Ssz);  // fold mean over S
  }

  bf16x8 qf[2][8];  // A-frags: lane = q-row
  {
    const short* qsrc = Qs + (size_t)(b * 64 + qt * 4 + wv) * 8192;
    #pragma unroll
    for (int mq = 0; mq < 2; ++mq)
      #pragma unroll
      for (int c = 0; c < 8; ++c)
        qf[mq][c] = *(const bf16x8*)&qsrc[(2 * c + h) * 512 + (mq * 32 + l31) * 8];
  }
  __syncthreads();  // linv ready

  float li[2][16];
  #pragma unroll
  for (int mq = 0; mq < 2; ++mq)
    #pragma unroll
    for (int r = 0; r < 16; ++r)
      li[mq][r] = linv_lds[wv * 64 + mq * 32 + (r & 3) + 8 * (r >> 2) + 4 * h];

  const char* kbase = (const char*)(Ks + (size_t)(b * 64 + kt * 8) * 8192);
  STAGE_K(0, 0);
  __syncthreads();

  for (int it = 0; it < 8; ++it) {
    const int cur = it & 1;
    if (it < 7) STAGE_K(it + 1, cur ^ 1);
    #pragma unroll
    for (int nk = 0; nk < 2; ++nk) {
      bf16x8 kf[8];  // B-frags: lane = k
      #pragma unroll
      for (int c = 0; c < 8; ++c)
        kf[c] = *(const bf16x8*)&kbuf[cur][(2 * c + h) * 512 + (nk * 32 + l31) * 8];
      f32x16 s0 = {}, s1 = {};
      #pragma unroll
      for (int c = 0; c < 8; ++c) {
        s0 = __builtin_amdgcn_mfma_f32_32x32x16_bf16(qf[0][c], kf[c], s0, 0, 0, 0);
        s1 = __builtin_amdgcn_mfma_f32_32x32x16_bf16(qf[1][c], kf[c], s1, 0, 0, 0);
      }
      float gp = 0.f;
      #pragma unroll
      for (int r = 0; r < 16; ++r)
        gp += li[0][r] * __builtin_amdgcn_exp2f(s0[r]) +
              li[1][r] * __builtin_amdgcn_exp2f(s1[r]);
      gp += __shfl_xor(gp, 32, 64);
      if (h == 0) gw[wv][it * 64 + nk * 32 + l31] = gp;
    }
    __syncthreads();
  }

  // combine 4 waves' g partials -> global
  float* gdst = gpart + (((size_t)(b * 16 + qt) * 8) + kt) * 512;
  #pragma unroll
  for (int j = 0; j < 2; ++j) {
    int idx = j * 256 + t;
    gdst[idx] = gw[0][idx] + gw[1][idx] + gw[2][idx] + gw[3][idx];
  }
}

// ---------------- GEMV: out[b,d] = sum_k G[b,k] V[k,d], G = sum_qt gpart ----------------
// grid (8 b, 32 ks): k-slice 128 per block. atomicAdd into zeroed fp32 d_out.
__global__ __launch_bounds__(256) void gemv_kernel(
    const float* __restrict__ gpart, const short* __restrict__ Vp,
    float* __restrict__ out) {
  __shared__ float Gs[128];
  __shared__ float pwb[512];
  const int b = blockIdx.x, ks = blockIdx.y;
  const int t = threadIdx.x;
  if (t < 128) {
    int k = ks * 128 + t;
    int kt = k >> 9, kl = k & 511;
    float s = 0.f;
    #pragma unroll
    for (int qt = 0; qt < 16; ++qt)
      s += gpart[((size_t)((b * 16 + qt) * 8 + kt)) * 512 + kl];
    Gs[t] = s;
  }
  __syncthreads();
  const int dp = t & 63, kq = t >> 6;  // d-pair, 32-k quarter
  const short* vr = Vp + ((size_t)b * 4096 + ks * 128 + kq * 32) * 128 + 2 * dp;
  float a0 = 0.f, a1 = 0.f;
  #pragma unroll 8
  for (int k = 0; k < 32; ++k) {
    u32 pair = *(const u32*)&vr[(size_t)k * 128];
    float g = Gs[kq * 32 + k];
    a0 += g * __uint_as_float(pair << 16);
    a1 += g * __uint_as_float(pair & 0xffff0000u);
  }
  pwb[kq * 128 + 2 * dp] = a0;
  pwb[kq * 128 + 2 * dp + 1] = a1;
  __syncthreads();
  if (t < 128) {
    float s = (pwb[t] + pwb[128 + t]) + (pwb[256 + t] + pwb[384 + t]);
    atomicAdd(&out[b * 128 + t], s);
  }
}

extern "C" void kernel_launch(void* const* d_in, const int* in_sizes, int n_in,
                              void* d_out, int out_size, void* d_ws, size_t ws_size,
                              hipStream_t stream) {
  const float* x = (const float*)d_in[0];  // fp32 [8,4096,128]
  const float* w = (const float*)d_in[1];  // fp32 [3,128,128]
  short* Qs = (short*)d_ws;                               // 8MB bf16 staged
  short* Ks = Qs + (size_t)Bsz * Ssz * Dsz;               // 8MB staged
  short* Vp = Ks + (size_t)Bsz * Ssz * Dsz;               // 8MB row-major
  float* lpart = (float*)(Vp + (size_t)Bsz * Ssz * Dsz);  // 1MB [kt8][b8][q4096]
  float* gpart = lpart + 8 * Bsz * Ssz;                   // 2MB [b8][qt16][kt8][k512]

  hipMemsetAsync(d_out, 0, Bsz * Dsz * sizeof(float), stream);
  proj_kernel<<<dim3(Bsz * Ssz / 64), dim3(256), 0, stream>>>(x, w, Qs, Ks, Vp);
  lsum_kernel<<<dim3(Bsz, 16, 8), dim3(256), 0, stream>>>(Qs, Ks, lpart);
  attnv_kernel<<<dim3(Bsz, 16, 8), dim3(256), 0, stream>>>(Qs, Ks, lpart, gpart);
  gemv_kernel<<<dim3(Bsz, 32), dim3(256), 0, stream>>>(gpart, Vp, (float*)d_out);
}

// Round 9
// 144.334 us; speedup vs baseline: 1.2744x; 1.2744x over previous
//
#include <hip/hip_runtime.h>

#define Bsz 8
#define Ssz 4096
#define Dsz 128

typedef short bf16x8 __attribute__((ext_vector_type(8)));
typedef float f32x4 __attribute__((ext_vector_type(4)));
typedef float f32x16 __attribute__((ext_vector_type(16)));
typedef int i32x2 __attribute__((ext_vector_type(2)));
typedef int i32x4 __attribute__((ext_vector_type(4)));
typedef unsigned int u32;

union B8 { u32 u[4]; bf16x8 v; };

__device__ __forceinline__ u32 pkbf(float a, float b) {
  u32 ra = __float_as_uint(a) + 0x8000u;
  u32 rb = __float_as_uint(b) + 0x8000u;
  return __builtin_amdgcn_perm(rb, ra, 0x07060302u);
}
__device__ __forceinline__ short f2bf(float f) {
  u32 r = __float_as_uint(f) + 0x8000u;
  return (short)(r >> 16);
}

__device__ __forceinline__ void gll16(const void* g, void* l) {
  __builtin_amdgcn_global_load_lds((const __attribute__((address_space(1))) void*)g,
                                   (__attribute__((address_space(3))) void*)l, 16, 0, 0);
}

// Staged Q/K layout (bf16), per 64-row tile (16KB): [gd 0..15][s 0..63][8 d].
// V plain row-major [s][d].

// ---------------- Projection ----------------
// grid 512 (64-row X tiles), 4 waves (wave owns e-slice 32).
// X: coalesced float4 reads -> bf16 LDS (padded stride 136) -> frags (conflict-free).
__global__ __launch_bounds__(256, 2) void proj_kernel(
    const float* __restrict__ x, const float* __restrict__ wsrc,
    short* __restrict__ Qs, short* __restrict__ Ks, short* __restrict__ Vp) {
  __shared__ short xb[64 * 136];  // 17.4KB
  __shared__ short ob[8192];      // 16KB output assembly

  const int rb = blockIdx.x;
  const int t = threadIdx.x;
  const int wv = t >> 6, lane = t & 63, l31 = lane & 31, h = lane >> 5;

  // coalesced X tile load: 64 rows x 128 f32 = 2048 float4
  {
    const float* xsrc = x + (size_t)rb * 64 * Dsz;
    #pragma unroll
    for (int p = 0; p < 8; ++p) {
      int idx4 = p * 256 + t;
      int row = idx4 >> 5;
      int c4 = (idx4 & 31) << 2;
      f32x4 v = *(const f32x4*)&xsrc[idx4 * 4];
      i32x2 pr;
      pr[0] = pkbf(v[0], v[1]);
      pr[1] = pkbf(v[2], v[3]);
      *(i32x2*)&xb[row * 136 + c4] = pr;
    }
  }
  __syncthreads();

  // X frags from LDS: lane = s row (l31), k = d = c*16 + 8h + j
  bf16x8 xf[2][8];
  #pragma unroll
  for (int st = 0; st < 2; ++st)
    #pragma unroll
    for (int c = 0; c < 8; ++c)
      xf[st][c] = *(const bf16x8*)&xb[(st * 32 + l31) * 136 + c * 16 + 8 * h];

  for (int mat = 0; mat < 3; ++mat) {
    const float* wm = wsrc + (size_t)mat * Dsz * Dsz;
    const float scale = (mat == 0) ? 1.44269504088896340736f : 1.0f;  // log2e in Wq
    bf16x8 wf[8];  // lane = e (wv*32+l31), k = d (coalesced 128B row chunks, L2-hot)
    #pragma unroll
    for (int c = 0; c < 8; ++c) {
      const float* p = wm + (size_t)(c * 16 + 8 * h) * Dsz + wv * 32 + l31;
      B8 tmp;
      #pragma unroll
      for (int j = 0; j < 4; ++j)
        tmp.u[j] = pkbf(p[(2 * j) * Dsz] * scale, p[(2 * j + 1) * Dsz] * scale);
      wf[c] = tmp.v;
    }

    if (mat < 2) {
      // C^T[e][s] = W(A,m=e) x X(B,n=s) -> staged [ge][s][8e]
      #pragma unroll
      for (int st = 0; st < 2; ++st) {
        f32x16 acc = {};
        #pragma unroll
        for (int c = 0; c < 8; ++c)
          acc = __builtin_amdgcn_mfma_f32_32x32x16_bf16(wf[c], xf[st][c], acc, 0, 0, 0);
        if (st == 0) __syncthreads();  // prev ob->global copy done
        #pragma unroll
        for (int g = 0; g < 4; ++g) {
          int e0 = wv * 32 + 8 * g + 4 * h;
          int s = st * 32 + l31;
          i32x2 pr;
          pr[0] = pkbf(acc[4 * g + 0], acc[4 * g + 1]);
          pr[1] = pkbf(acc[4 * g + 2], acc[4 * g + 3]);
          *(i32x2*)&ob[(e0 >> 3) * 512 + s * 8 + (e0 & 7)] = pr;
        }
      }
    } else {
      // C[s][e] = X(A,m=s) x W(B,n=e) -> row-major ob[s][e]
      #pragma unroll
      for (int st = 0; st < 2; ++st) {
        f32x16 acc = {};
        #pragma unroll
        for (int c = 0; c < 8; ++c)
          acc = __builtin_amdgcn_mfma_f32_32x32x16_bf16(xf[st][c], wf[c], acc, 0, 0, 0);
        if (st == 0) __syncthreads();
        int e = wv * 32 + l31;
        #pragma unroll
        for (int r = 0; r < 16; ++r) {
          int s = st * 32 + (r & 3) + 8 * (r >> 2) + 4 * h;
          ob[s * 128 + e] = f2bf(acc[r]);
        }
      }
    }
    __syncthreads();
    short* dst = (mat == 0 ? Qs : mat == 1 ? Ks : Vp) + (size_t)rb * 8192;
    #pragma unroll
    for (int p = 0; p < 4; ++p)
      *(i32x4*)&dst[(p * 256 + t) * 8] = *(const i32x4*)&ob[(p * 256 + t) * 8];
  }
}

// ---------------- Phase A: softmax denominators ----------------
// grid (8 b, 16 qt, 4 kt) = 512 blocks @ 2/CU (L2-safe, R7-proven).
// q-tile 256 (wave owns 64 q), k-range 1024, 128-k chunks x 8 iters.
__global__ __launch_bounds__(256, 2) void lsum_kernel(
    const short* __restrict__ Qs, const short* __restrict__ Ks,
    float* __restrict__ lpart) {
  __shared__ short kbuf[2][16384];  // 2 x 32KB (two 64-row staged tiles each)

  const int b = blockIdx.x, qt = blockIdx.y, kt = blockIdx.z;
  const int t = threadIdx.x;
  const int wv = t >> 6, lane = t & 63, l31 = lane & 31, h = lane >> 5;

  // Q B-frags: lane = q, k = d
  bf16x8 qf[2][8];
  {
    const short* qsrc = Qs + (size_t)(b * 64 + qt * 4 + wv) * 8192;
    #pragma unroll
    for (int nq = 0; nq < 2; ++nq)
      #pragma unroll
      for (int c = 0; c < 8; ++c)
        qf[nq][c] = *(const bf16x8*)&qsrc[(2 * c + h) * 512 + (nq * 32 + l31) * 8];
  }
  float rs2[2] = {0.f, 0.f};

  const char* kbase = (const char*)(Ks + (size_t)(b * 64 + kt * 16) * 8192);
  #define STAGE_K2(it_, bf_)                                                    \
    { const char* src_ = kbase + (size_t)(it_) * 32768;                         \
      _Pragma("unroll")                                                         \
      for (int i_ = 0; i_ < 8; ++i_) {                                          \
        int p_ = wv * 8 + i_;                                                   \
        gll16(src_ + p_ * 1024 + lane * 16, (char*)kbuf[bf_] + p_ * 1024);      \
      } }

  STAGE_K2(0, 0);
  __syncthreads();

  for (int it = 0; it < 8; ++it) {
    const int cur = it & 1;
    if (it < 7) STAGE_K2(it + 1, cur ^ 1);
    #pragma unroll
    for (int mk = 0; mk < 4; ++mk) {
      bf16x8 kf[8];  // A-frags: lane = k-row
      #pragma unroll
      for (int c = 0; c < 8; ++c)
        kf[c] = *(const bf16x8*)&kbuf[cur][(mk >> 1) * 8192 + (2 * c + h) * 512 +
                                           ((mk & 1) * 32 + l31) * 8];
      f32x16 s0 = {}, s1 = {};
      #pragma unroll
      for (int c = 0; c < 8; ++c) {
        s0 = __builtin_amdgcn_mfma_f32_32x32x16_bf16(kf[c], qf[0][c], s0, 0, 0, 0);
        s1 = __builtin_amdgcn_mfma_f32_32x32x16_bf16(kf[c], qf[1][c], s1, 0, 0, 0);
      }
      #pragma unroll
      for (int r = 0; r < 16; ++r) rs2[0] += __builtin_amdgcn_exp2f(s0[r]);
      #pragma unroll
      for (int r = 0; r < 16; ++r) rs2[1] += __builtin_amdgcn_exp2f(s1[r]);
    }
    __syncthreads();
  }

  #pragma unroll
  for (int nq = 0; nq < 2; ++nq) {
    float v = rs2[nq] + __shfl_xor(rs2[nq], 32, 64);
    if (h == 0)
      lpart[((size_t)kt * 8 + b) * 4096 + qt * 256 + wv * 64 + nq * 32 + l31] = v;
  }
}

// ---------------- Phase B: g-partials gpart[b,qt,kt][k] = sum_q linv[q] exp(S) ----------------
// grid (8,16,4) = 512 @ 2/CU. 64-k chunks x 16 iters (gw LDS budget).
__global__ __launch_bounds__(256, 2) void attnv_kernel(
    const short* __restrict__ Qs, const short* __restrict__ Ks,
    const float* __restrict__ lpart, float* __restrict__ gpart) {
  __shared__ short kbuf[2][8192];  // 2 x 16KB
  __shared__ float linv_lds[256];
  __shared__ float gw[4][1024];    // 16KB

  const int b = blockIdx.x, qt = blockIdx.y, kt = blockIdx.z;
  const int t = threadIdx.x;
  const int wv = t >> 6, lane = t & 63, l31 = lane & 31, h = lane >> 5;

  {  // denominators for this block's 256 q (sum over 4 kt partials)
    int q = qt * 256 + t;
    float l = 0.f;
    #pragma unroll
    for (int k2 = 0; k2 < 4; ++k2) l += lpart[((size_t)k2 * 8 + b) * 4096 + q];
    linv_lds[t] = 1.f / (l * (float)Ssz);  // fold mean over S
  }

  bf16x8 qf[2][8];  // A-frags: lane = q-row
  {
    const short* qsrc = Qs + (size_t)(b * 64 + qt * 4 + wv) * 8192;
    #pragma unroll
    for (int mq = 0; mq < 2; ++mq)
      #pragma unroll
      for (int c = 0; c < 8; ++c)
        qf[mq][c] = *(const bf16x8*)&qsrc[(2 * c + h) * 512 + (mq * 32 + l31) * 8];
  }
  __syncthreads();  // linv ready

  float li[2][16];
  #pragma unroll
  for (int mq = 0; mq < 2; ++mq)
    #pragma unroll
    for (int r = 0; r < 16; ++r)
      li[mq][r] = linv_lds[wv * 64 + mq * 32 + (r & 3) + 8 * (r >> 2) + 4 * h];

  const char* kbase = (const char*)(Ks + (size_t)(b * 64 + kt * 16) * 8192);
  #define STAGE_K1(it_, bf_)                                                    \
    { const char* src_ = kbase + (size_t)(it_) * 16384;                         \
      _Pragma("unroll")                                                         \
      for (int i_ = 0; i_ < 4; ++i_) {                                          \
        int p_ = wv * 4 + i_;                                                   \
        gll16(src_ + p_ * 1024 + lane * 16, (char*)kbuf[bf_] + p_ * 1024);      \
      } }

  STAGE_K1(0, 0);
  __syncthreads();

  for (int it = 0; it < 16; ++it) {
    const int cur = it & 1;
    if (it < 15) STAGE_K1(it + 1, cur ^ 1);
    #pragma unroll
    for (int nk = 0; nk < 2; ++nk) {
      bf16x8 kf[8];  // B-frags: lane = k
      #pragma unroll
      for (int c = 0; c < 8; ++c)
        kf[c] = *(const bf16x8*)&kbuf[cur][(2 * c + h) * 512 + (nk * 32 + l31) * 8];
      f32x16 s0 = {}, s1 = {};
      #pragma unroll
      for (int c = 0; c < 8; ++c) {
        s0 = __builtin_amdgcn_mfma_f32_32x32x16_bf16(qf[0][c], kf[c], s0, 0, 0, 0);
        s1 = __builtin_amdgcn_mfma_f32_32x32x16_bf16(qf[1][c], kf[c], s1, 0, 0, 0);
      }
      float gp = 0.f;
      #pragma unroll
      for (int r = 0; r < 16; ++r)
        gp += li[0][r] * __builtin_amdgcn_exp2f(s0[r]) +
              li[1][r] * __builtin_amdgcn_exp2f(s1[r]);
      gp += __shfl_xor(gp, 32, 64);
      if (h == 0) gw[wv][it * 64 + nk * 32 + l31] = gp;
    }
    __syncthreads();
  }

  float* gdst = gpart + (((size_t)(b * 16 + qt) * 4) + kt) * 1024;
  #pragma unroll
  for (int j = 0; j < 4; ++j) {
    int idx = j * 256 + t;
    gdst[idx] = (gw[0][idx] + gw[1][idx]) + (gw[2][idx] + gw[3][idx]);
  }
}

// ---------------- GEMV: out[b,d] = sum_k G[b,k] V[k,d] ----------------
__global__ __launch_bounds__(256) void gemv_kernel(
    const float* __restrict__ gpart, const short* __restrict__ Vp,
    float* __restrict__ out) {
  __shared__ float Gs[128];
  __shared__ float pwb[512];
  const int b = blockIdx.x, ks = blockIdx.y;
  const int t = threadIdx.x;
  if (t < 128) {
    int k = ks * 128 + t;
    int kt = k >> 10, kl = k & 1023;
    float s = 0.f;
    #pragma unroll
    for (int qt = 0; qt < 16; ++qt)
      s += gpart[(((size_t)(b * 16 + qt) * 4) + kt) * 1024 + kl];
    Gs[t] = s;
  }
  __syncthreads();
  const int dp = t & 63, kq = t >> 6;  // d-pair, 32-k quarter
  const short* vr = Vp + ((size_t)b * 4096 + ks * 128 + kq * 32) * 128 + 2 * dp;
  float a0 = 0.f, a1 = 0.f;
  #pragma unroll 8
  for (int k = 0; k < 32; ++k) {
    u32 pair = *(const u32*)&vr[(size_t)k * 128];
    float g = Gs[kq * 32 + k];
    a0 += g * __uint_as_float(pair << 16);
    a1 += g * __uint_as_float(pair & 0xffff0000u);
  }
  pwb[kq * 128 + 2 * dp] = a0;
  pwb[kq * 128 + 2 * dp + 1] = a1;
  __syncthreads();
  if (t < 128) {
    float s = (pwb[t] + pwb[128 + t]) + (pwb[256 + t] + pwb[384 + t]);
    atomicAdd(&out[b * 128 + t], s);
  }
}

extern "C" void kernel_launch(void* const* d_in, const int* in_sizes, int n_in,
                              void* d_out, int out_size, void* d_ws, size_t ws_size,
                              hipStream_t stream) {
  const float* x = (const float*)d_in[0];  // fp32 [8,4096,128]
  const float* w = (const float*)d_in[1];  // fp32 [3,128,128]
  short* Qs = (short*)d_ws;                               // 8MB bf16 staged
  short* Ks = Qs + (size_t)Bsz * Ssz * Dsz;               // 8MB staged
  short* Vp = Ks + (size_t)Bsz * Ssz * Dsz;               // 8MB row-major
  float* lpart = (float*)(Vp + (size_t)Bsz * Ssz * Dsz);  // 512KB [kt4][b8][q4096]
  float* gpart = lpart + 4 * Bsz * Ssz;                   // 2MB [b8][qt16][kt4][k1024]

  hipMemsetAsync(d_out, 0, Bsz * Dsz * sizeof(float), stream);
  proj_kernel<<<dim3(Bsz * Ssz / 64), dim3(256), 0, stream>>>(x, w, Qs, Ks, Vp);
  lsum_kernel<<<dim3(Bsz, 16, 4), dim3(256), 0, stream>>>(Qs, Ks, lpart);
  attnv_kernel<<<dim3(Bsz, 16, 4), dim3(256), 0, stream>>>(Qs, Ks, lpart, gpart);
  gemv_kernel<<<dim3(Bsz, 32), dim3(256), 0, stream>>>(gpart, Vp, (float*)d_out);
}